// Round 3
// baseline (580.006 us; speedup 1.0000x reference)
//
#include <hip/hip_runtime.h>
#include <hip/hip_bf16.h>

// Problem constants (reference: BS=32, N=512)
#define BSZ 32
#define NN  512

// Output flat offsets (elements, f32), in reference return order:
//  X_cat [32,512,32]       = 524288
//  C_cat [32,512,6]        =  98304
//  E1    [32,512,512,5]    = 41943040
//  E2    [32,512,512,5]    = 41943040
//  BD1   [32,512,512,3]    = 25165824
static const long O_XC = 0;
static const long O_CC = 524288L;
static const long O_E1 = 622592L;
static const long O_E2 = 42565632L;
static const long O_BD = 84508672L;

// ---------------------------------------------------------------------------
// Kernel A: per-sample alignment map.
// p2m[i*N+j] = product position aligned to reactant j, or -1 if unmapped.
// Mirrors _alignment_maps: prod_assign = rowmax(mol_assignment);
// inverse table over product amn; reactant amn filtered by presence.
// ---------------------------------------------------------------------------
__global__ __launch_bounds__(NN) void align_kernel(
    const int* __restrict__ amn, const int* __restrict__ ma,
    int* __restrict__ p2m)
{
    const int i = blockIdx.x;
    const int t = threadIdx.x;          // 0..511

    __shared__ int red[NN];
    __shared__ int table[NN + 1];

    const int a = ma[i * NN + t];
    red[t] = a;
    __syncthreads();
    for (int s = NN / 2; s > 0; s >>= 1) {
        if (t < s) red[t] = max(red[t], red[t + s]);
        __syncthreads();
    }
    const int prod_assign = red[0];     // safe: last loop iter ended in sync

    table[t] = -1;
    if (t == 0) table[NN] = -1;
    __syncthreads();

    const int m = amn[i * NN + t];
    if (a == prod_assign && m > 0 && m <= NN) table[m] = t;
    __syncthreads();

    int p = -1;
    if (a < prod_assign && m > 0 && m <= NN) p = table[m];   // -1 if absent in product
    p2m[i * NN + t] = p;
}

// ---------------------------------------------------------------------------
// Kernel B: node features. One thread per (i,j) row. f32 in, f32 out.
// X_cat = [X | gather(X, p)*mask], C_cat = [C | gather(C, p)*mask]
// ---------------------------------------------------------------------------
__global__ __launch_bounds__(256) void node_kernel(
    const float* __restrict__ X,
    const float* __restrict__ AC,
    const int* __restrict__ p2m,
    float* __restrict__ out)
{
    const int idx = blockIdx.x * 256 + threadIdx.x;
    if (idx >= BSZ * NN) return;
    const int i = idx >> 9;
    const int p = p2m[idx];

    const float* xr = X + (size_t)idx * 16;
    float* ox = out + O_XC + (size_t)idx * 32;
#pragma unroll
    for (int c = 0; c < 16; ++c) ox[c] = xr[c];
    if (p >= 0) {
        const float* xp = X + ((size_t)i * NN + p) * 16;
#pragma unroll
        for (int c = 0; c < 16; ++c) ox[16 + c] = xp[c];
    } else {
#pragma unroll
        for (int c = 0; c < 16; ++c) ox[16 + c] = 0.0f;
    }

    const float* cr = AC + (size_t)idx * 3;
    float* oc = out + O_CC + (size_t)idx * 6;
#pragma unroll
    for (int c = 0; c < 3; ++c) oc[c] = cr[c];
    if (p >= 0) {
        const float* cp = AC + ((size_t)i * NN + p) * 3;
#pragma unroll
        for (int c = 0; c < 3; ++c) oc[3 + c] = cp[c];
    } else {
#pragma unroll
        for (int c = 0; c < 3; ++c) oc[3 + c] = 0.0f;
    }
}

// ---------------------------------------------------------------------------
// Kernel C: edge features. One block per (i,j1); thread per j2. f32 in/out.
// E1 = gather_pairs(E)*pair, E2 = (1-pair)*onehot0, BD1 = gather_pairs(BD)*pair
// ---------------------------------------------------------------------------
__global__ __launch_bounds__(NN) void edge_kernel(
    const float* __restrict__ E,
    const float* __restrict__ BD,
    const int* __restrict__ p2m,
    float* __restrict__ out)
{
    const int b  = blockIdx.x;          // i*N + j1
    const int i  = b >> 9;
    const int j1 = b & (NN - 1);
    const int j2 = threadIdx.x;

    __shared__ int sp[NN];
    sp[j2] = p2m[i * NN + j2];
    __syncthreads();

    const int p1 = sp[j1];
    const int p2 = sp[j2];

    const size_t pairo = (size_t)b * NN + j2;
    float* e1 = out + O_E1 + pairo * 5;
    float* e2 = out + O_E2 + pairo * 5;
    float* bd = out + O_BD + pairo * 3;

    if (p1 >= 0 && p2 >= 0) {
        const size_t src = ((size_t)i * NN + p1) * NN + p2;
        const float* es = E + src * 5;
        const float* bs = BD + src * 3;
#pragma unroll
        for (int c = 0; c < 5; ++c) e1[c] = es[c];
#pragma unroll
        for (int c = 0; c < 5; ++c) e2[c] = 0.0f;
#pragma unroll
        for (int c = 0; c < 3; ++c) bd[c] = bs[c];
    } else {
#pragma unroll
        for (int c = 0; c < 5; ++c) e1[c] = 0.0f;
        e2[0] = 1.0f;
#pragma unroll
        for (int c = 1; c < 5; ++c) e2[c] = 0.0f;
#pragma unroll
        for (int c = 0; c < 3; ++c) bd[c] = 0.0f;
    }
}

extern "C" void kernel_launch(void* const* d_in, const int* in_sizes, int n_in,
                              void* d_out, int out_size, void* d_ws, size_t ws_size,
                              hipStream_t stream) {
    const float* X  = (const float*)d_in[0];
    const float* E  = (const float*)d_in[1];
    const float* AC = (const float*)d_in[2];
    const float* BD = (const float*)d_in[3];
    const int* amn = (const int*)d_in[4];
    const int* ma  = (const int*)d_in[5];
    float* out = (float*)d_out;

    int* p2m = (int*)d_ws;   // 32*512 ints = 64 KB

    align_kernel<<<BSZ, NN, 0, stream>>>(amn, ma, p2m);
    node_kernel<<<(BSZ * NN + 255) / 256, 256, 0, stream>>>(X, AC, p2m, out);
    edge_kernel<<<BSZ * NN, NN, 0, stream>>>(E, BD, p2m, out);
}

// Round 4
// 570.466 us; speedup vs baseline: 1.0167x; 1.0167x over previous
//
#include <hip/hip_runtime.h>
#include <hip/hip_bf16.h>

// Problem constants (reference: BS=32, N=512)
#define BSZ 32
#define NN  512

// Output flat offsets (elements, f32), in reference return order:
//  X_cat [32,512,32]       = 524288
//  C_cat [32,512,6]        =  98304
//  E1    [32,512,512,5]    = 41943040
//  E2    [32,512,512,5]    = 41943040
//  BD1   [32,512,512,3]    = 25165824
static const long O_XC = 0;
static const long O_CC = 524288L;
static const long O_E1 = 622592L;
static const long O_E2 = 42565632L;
static const long O_BD = 84508672L;

// ---------------------------------------------------------------------------
// Kernel A: per-sample alignment map (unchanged — trivial cost).
// p2m[i*N+j] = product position aligned to reactant j, or -1 if unmapped.
// ---------------------------------------------------------------------------
__global__ __launch_bounds__(NN) void align_kernel(
    const int* __restrict__ amn, const int* __restrict__ ma,
    int* __restrict__ p2m)
{
    const int i = blockIdx.x;
    const int t = threadIdx.x;          // 0..511

    __shared__ int red[NN];
    __shared__ int table[NN + 1];

    const int a = ma[i * NN + t];
    red[t] = a;
    __syncthreads();
    for (int s = NN / 2; s > 0; s >>= 1) {
        if (t < s) red[t] = max(red[t], red[t + s]);
        __syncthreads();
    }
    const int prod_assign = red[0];

    table[t] = -1;
    if (t == 0) table[NN] = -1;
    __syncthreads();

    const int m = amn[i * NN + t];
    if (a == prod_assign && m > 0 && m <= NN) table[m] = t;
    __syncthreads();

    int p = -1;
    if (a < prod_assign && m > 0 && m <= NN) p = table[m];
    p2m[i * NN + t] = p;
}

// ---------------------------------------------------------------------------
// Kernel B: node features, float4-vectorized X path. One thread per (i,j).
// ---------------------------------------------------------------------------
__global__ __launch_bounds__(256) void node_kernel(
    const float* __restrict__ X,
    const float* __restrict__ AC,
    const int* __restrict__ p2m,
    float* __restrict__ out)
{
    const int idx = blockIdx.x * 256 + threadIdx.x;
    if (idx >= BSZ * NN) return;
    const int i = idx >> 9;
    const int p = p2m[idx];

    const float4* xr4 = (const float4*)(X + (size_t)idx * 16);
    float4* ox4 = (float4*)(out + O_XC + (size_t)idx * 32);
#pragma unroll
    for (int c = 0; c < 4; ++c) ox4[c] = xr4[c];
    if (p >= 0) {
        const float4* xp4 = (const float4*)(X + ((size_t)i * NN + p) * 16);
#pragma unroll
        for (int c = 0; c < 4; ++c) ox4[4 + c] = xp4[c];
    } else {
        const float4 z = make_float4(0.f, 0.f, 0.f, 0.f);
#pragma unroll
        for (int c = 0; c < 4; ++c) ox4[4 + c] = z;
    }

    const float* cr = AC + (size_t)idx * 3;
    float* oc = out + O_CC + (size_t)idx * 6;
#pragma unroll
    for (int c = 0; c < 3; ++c) oc[c] = cr[c];
    if (p >= 0) {
        const float* cp = AC + ((size_t)i * NN + p) * 3;
#pragma unroll
        for (int c = 0; c < 3; ++c) oc[3 + c] = cp[c];
    } else {
#pragma unroll
        for (int c = 0; c < 3; ++c) oc[3 + c] = 0.0f;
    }
}

// ---------------------------------------------------------------------------
// Kernel C: edge features, OUTPUT-FLAT. One block per (i,j1) row.
// Threads map onto consecutive float4s of each output region:
//   E1 row = 640 float4s, E2 row = 640, BD row = 384.
// Every global store is a fully-coalesced dwordx4 (memset-like pattern).
// Source values: predicated scalar loads from the gathered product row
// (10 KB span, read exactly once per sample -> L1/L2 friendly).
// ---------------------------------------------------------------------------
__global__ __launch_bounds__(NN) void edge_kernel(
    const float* __restrict__ E,
    const float* __restrict__ BD,
    const int* __restrict__ p2m,
    float* __restrict__ out)
{
    const int b  = blockIdx.x;          // i*N + j1
    const int i  = b >> 9;
    const int j1 = b & (NN - 1);
    const int t  = threadIdx.x;

    __shared__ int sp[NN];
    sp[t] = p2m[i * NN + t];
    __syncthreads();

    const int p1  = sp[j1];
    const int p1c = p1 < 0 ? 0 : p1;
    const float* __restrict__ Erow = E  + ((size_t)i * NN + p1c) * NN * 5;
    const float* __restrict__ Brow = BD + ((size_t)i * NN + p1c) * NN * 3;

    float4* oE1 = (float4*)(out + O_E1 + (size_t)b * (NN * 5));
    float4* oE2 = (float4*)(out + O_E2 + (size_t)b * (NN * 5));
    float4* oBD = (float4*)(out + O_BD + (size_t)b * (NN * 3));

    // E1: gathered product edges, masked
    for (int f = t; f < 640; f += NN) {
        float4 v;
        float* vv = (float*)&v;
#pragma unroll
        for (int k = 0; k < 4; ++k) {
            const int g  = 4 * f + k;
            const int j2 = g / 5;           // compiler magic-mul
            const int c  = g - j2 * 5;
            const int p2 = sp[j2];
            float x = 0.0f;
            if (p1 >= 0 && p2 >= 0) x = Erow[p2 * 5 + c];
            vv[k] = x;
        }
        oE1[f] = v;
    }

    // E2: (1-pair)*onehot0 — pure compute, no loads
    for (int f = t; f < 640; f += NN) {
        float4 v;
        float* vv = (float*)&v;
#pragma unroll
        for (int k = 0; k < 4; ++k) {
            const int g  = 4 * f + k;
            const int j2 = g / 5;
            const int c  = g - j2 * 5;
            const int p2 = sp[j2];
            vv[k] = (p1 >= 0 && p2 >= 0) ? 0.0f : (c == 0 ? 1.0f : 0.0f);
        }
        oE2[f] = v;
    }

    // BD1: gathered bond dirs, masked
    for (int f = t; f < 384; f += NN) {
        float4 v;
        float* vv = (float*)&v;
#pragma unroll
        for (int k = 0; k < 4; ++k) {
            const int g  = 4 * f + k;
            const int j2 = g / 3;
            const int c  = g - j2 * 3;
            const int p2 = sp[j2];
            float x = 0.0f;
            if (p1 >= 0 && p2 >= 0) x = Brow[p2 * 3 + c];
            vv[k] = x;
        }
        oBD[f] = v;
    }
}

extern "C" void kernel_launch(void* const* d_in, const int* in_sizes, int n_in,
                              void* d_out, int out_size, void* d_ws, size_t ws_size,
                              hipStream_t stream) {
    const float* X  = (const float*)d_in[0];
    const float* E  = (const float*)d_in[1];
    const float* AC = (const float*)d_in[2];
    const float* BD = (const float*)d_in[3];
    const int* amn = (const int*)d_in[4];
    const int* ma  = (const int*)d_in[5];
    float* out = (float*)d_out;

    int* p2m = (int*)d_ws;   // 32*512 ints = 64 KB

    align_kernel<<<BSZ, NN, 0, stream>>>(amn, ma, p2m);
    node_kernel<<<(BSZ * NN + 255) / 256, 256, 0, stream>>>(X, AC, p2m, out);
    edge_kernel<<<BSZ * NN, NN, 0, stream>>>(E, BD, p2m, out);
}